// Round 2
// baseline (570.454 us; speedup 1.0000x reference)
//
#include <hip/hip_runtime.h>
#include <math.h>

#define N_CELLS 8192
#define TOPK 8

// ws float layout:
//      0: signal[128]
//    128: dists[8192]
//   8320: partial[256*128]   per-block faction-column partial sums (no atomics)
//  41088: topd[8]
//  41096: topi[8]   (int)
//  41104: nlist     (int)
//  41112: listIdx[8192] (int)   affected cells (a != 1)
//  49304: listA[8192]  (float)  their affine coefficient a

__global__ __launch_bounds__(128) void k_signal(const float* __restrict__ x,
                                                const float* __restrict__ in_w,
                                                const float* __restrict__ in_b,
                                                float* __restrict__ signal) {
    int j = threadIdx.x;  // 0..127
    float acc = in_b[j];
    const float* w = in_w + j * 64;
    #pragma unroll
    for (int k = 0; k < 64; ++k) acc += x[k] * w[k];
    signal[j] = acc;
}

// 256 blocks x 256 threads; one wave per cell-row (float2/lane = full 512B row).
// Block covers 32 contiguous cells (all one faction: 32 blocks/faction).
__global__ __launch_bounds__(256) void k_dist(const float* __restrict__ proto,
                                              const float* __restrict__ signal,
                                              float* __restrict__ dists,
                                              float* __restrict__ partial) {
    __shared__ float sm[512];
    int tid = threadIdx.x;
    int wave = tid >> 6, lane = tid & 63;
    float2 s2 = ((const float2*)signal)[lane];
    float fx = 0.0f, fy = 0.0f;
    int base = blockIdx.x * 32;
    for (int c = wave; c < 32; c += 4) {
        int cell = base + c;
        float2 p = ((const float2*)(proto + (size_t)cell * 128))[lane];
        float dx = p.x - s2.x, dy = p.y - s2.y;
        float d = dx * dx + dy * dy;
        #pragma unroll
        for (int off = 32; off > 0; off >>= 1) d += __shfl_down(d, off, 64);
        if (lane == 0) dists[cell] = d;
        fx += p.x; fy += p.y;
    }
    sm[wave * 128 + 2 * lane]     = fx;
    sm[wave * 128 + 2 * lane + 1] = fy;
    __syncthreads();
    if (tid < 128)
        partial[blockIdx.x * 128 + tid] = sm[tid] + sm[128 + tid] + sm[256 + tid] + sm[384 + tid];
}

// Single block, 512 threads: stable top-8 argmin passes, then scan edges/ages
// ROW bmu1 once (64KB coalesced) emitting the sparse affected-cell list.
__global__ __launch_bounds__(512) void k_topcoef(const float* __restrict__ dists_g,
                                                 const float* __restrict__ edges,
                                                 const float* __restrict__ ages,
                                                 const int* __restrict__ step_p,
                                                 float* __restrict__ topd,
                                                 int* __restrict__ topi,
                                                 int* __restrict__ nlist,
                                                 int* __restrict__ listIdx,
                                                 float* __restrict__ listA) {
    __shared__ float sd[N_CELLS];   // 32 KB
    __shared__ float sv[512];
    __shared__ int   si[512];
    __shared__ int   sbmu[8];
    __shared__ int   lcnt;
    int t = threadIdx.x;
    if (t == 0) lcnt = 0;
    for (int j = 0; j < 16; ++j) sd[j * 512 + t] = dists_g[j * 512 + t];
    __syncthreads();
    for (int k = 0; k < TOPK; ++k) {
        float lv = INFINITY; int li = N_CELLS;
        #pragma unroll
        for (int j = 0; j < 16; ++j) {
            int   ii = j * 512 + t;
            float vv = sd[ii];
            if (vv < lv || (vv == lv && ii < li)) { lv = vv; li = ii; }
        }
        sv[t] = lv; si[t] = li;
        __syncthreads();
        for (int s = 256; s > 0; s >>= 1) {
            if (t < s) {
                float ov = sv[t + s]; int oi = si[t + s];
                if (ov < sv[t] || (ov == sv[t] && oi < si[t])) { sv[t] = ov; si[t] = oi; }
            }
            __syncthreads();
        }
        if (t == 0) {
            topd[k] = sv[0]; topi[k] = si[0]; sbmu[k] = si[0];
            sd[si[0]] = INFINITY;
        }
        __syncthreads();
    }
    int bmu1 = sbmu[0], bmu2 = sbmu[1];
    float step = (float)step_p[0];
    float eps_w = fmaxf(0.05f, 0.3f * expf(-step / 200.0f));
    float eps_n = eps_w * 0.01f;
    const float* erow = edges + (size_t)bmu1 * N_CELLS;
    const float* arow = ages  + (size_t)bmu1 * N_CELLS;
    for (int i = t; i < N_CELLS; i += 512) {
        float age, ec;
        if (i == bmu2)      { age = 1.0f;          ec = 1.0f; }
        else if (i == bmu1) { age = arow[i] + 2.0f; ec = erow[i]; }
        else                { age = arow[i] + 1.0f; ec = erow[i]; }
        bool nb = ((age > 50.0f) ? 0.0f : ec) > 0.0f;
        float a = 1.0f;
        if (i == bmu1) a *= (1.0f - eps_w);
        if (i == bmu2) a *= (1.0f - eps_n);
        if (nb)        a *= (1.0f - eps_n);
        if (a != 1.0f) {
            int pos = atomicAdd(&lcnt, 1);
            listIdx[pos] = i;
            listA[pos]   = a;
        }
    }
    __syncthreads();
    if (t == 0) *nlist = lcnt;
}

// Single block, 256 threads (4 waves). Faction means from partials + sparse
// corrections, softmax-weighted 8-row reconstruction, expert MLPs + tension,
// output GEMV — all row-dots are coalesced wave-per-row float2 + shuffle reduce.
__global__ __launch_bounds__(256) void k_final(const float* __restrict__ proto,
                                               const float* __restrict__ signal,
                                               const float* __restrict__ partial,
                                               const float* __restrict__ topd_g,
                                               const int* __restrict__ topi_g,
                                               const int* __restrict__ nlist,
                                               const int* __restrict__ listIdx,
                                               const float* __restrict__ listA,
                                               const float* __restrict__ edges,
                                               const float* __restrict__ ages,
                                               const int* __restrict__ step_p,
                                               const float* __restrict__ ea_w1,
                                               const float* __restrict__ ea_b1,
                                               const float* __restrict__ ea_w2,
                                               const float* __restrict__ ea_b2,
                                               const float* __restrict__ eg_w1,
                                               const float* __restrict__ eg_b1,
                                               const float* __restrict__ eg_w2,
                                               const float* __restrict__ eg_b2,
                                               const float* __restrict__ out_w,
                                               const float* __restrict__ out_b,
                                               float* __restrict__ d_out) {
    __shared__ __align__(16) float csumS[1024];
    __shared__ __align__(16) float fmS[1024];
    __shared__ float BfS[8];
    __shared__ __align__(16) float wh[128];
    __shared__ __align__(16) float cmb[128];
    __shared__ __align__(16) float hA[128];
    __shared__ __align__(16) float hG[128];
    __shared__ float aout[64], gout[64];
    __shared__ float tda[8];
    __shared__ int   tia[8];
    int t = threadIdx.x;
    int n = *nlist;
    int step = step_p[0];
    if (t < 8) { tda[t] = topd_g[t]; tia[t] = topi_g[t]; }
    if (t < 128) {
        #pragma unroll
        for (int f = 0; f < 8; ++f) csumS[f * 128 + t] = 0.0f;
    }
    __syncthreads();
    if (t < 128) {
        int d = t;
        for (int e = 0; e < n; ++e) {
            int idx = listIdx[e]; float a = listA[e];
            csumS[(idx >> 10) * 128 + d] += (a - 1.0f) * proto[(size_t)idx * 128 + d];
        }
    } else if (t < 136) {
        int f = t - 128; float acc = 0.0f;
        for (int e = 0; e < n; ++e)
            if ((listIdx[e] >> 10) == f) acc += 1.0f - listA[e];
        BfS[f] = acc;
    }
    __syncthreads();
    if (t < 128) {
        int d = t;
        float s = signal[d];
        float g = 0.0f;
        #pragma unroll
        for (int f = 0; f < 8; ++f) {
            float acc = 0.0f;
            for (int b = 0; b < 32; ++b) acc += partial[(f * 32 + b) * 128 + d];
            float v = (acc + csumS[f * 128 + d] + BfS[f] * s) * (1.0f / 1024.0f);
            fmS[f * 128 + d] = v; g += v;
        }
        g *= 0.125f;
        float wk[TOPK]; float tot = 0.0f; float m = tda[0];
        #pragma unroll
        for (int k = 0; k < TOPK; ++k) { wk[k] = expf(-(tda[k] - m)); tot += wk[k]; }
        float inv = 1.0f / tot;
        int bmu1 = tia[0], bmu2 = tia[1];
        float stf = (float)step;
        float eps_w = fmaxf(0.05f, 0.3f * expf(-stf / 200.0f));
        float eps_n = eps_w * 0.01f;
        float comb = 0.0f, win = 0.0f;
        #pragma unroll
        for (int k = 0; k < TOPK; ++k) {
            int idx = tia[k];
            size_t ro = (size_t)bmu1 * N_CELLS + (size_t)idx;
            float age, ec;
            if (idx == bmu2)      { age = 1.0f;            ec = 1.0f; }
            else if (idx == bmu1) { age = ages[ro] + 2.0f;  ec = edges[ro]; }
            else                  { age = ages[ro] + 1.0f;  ec = edges[ro]; }
            bool nb = ((age > 50.0f) ? 0.0f : ec) > 0.0f;
            float a = 1.0f;
            if (idx == bmu1) a *= (1.0f - eps_w);
            if (idx == bmu2) a *= (1.0f - eps_n);
            if (nb)          a *= (1.0f - eps_n);
            float p1 = a * proto[(size_t)idx * 128 + d] + (1.0f - a) * s;
            float pf = 0.85f * p1 + 0.15f * fmS[(idx >> 10) * 128 + d];
            if (step > 5 && (idx & 1023) < 256) pf = 0.85f * pf + 0.15f * g;
            comb += wk[k] * inv * pf;
            if (k == 0) win = pf;
        }
        wh[d] = win; cmb[d] = comb;
    }
    __syncthreads();
    // hidden layers: 256 coalesced row-dots, 64 per wave
    int wave = t >> 6, lane = t & 63;
    for (int q = 0; q < 64; ++q) {
        int task = wave * 64 + q;
        int row = task & 127;
        const float* W = (task < 128) ? ea_w1 : eg_w1;
        float2 wv = ((const float2*)(W + row * 128))[lane];
        float2 hv = ((const float2*)wh)[lane];
        float acc = wv.x * hv.x + wv.y * hv.y;
        #pragma unroll
        for (int off = 32; off > 0; off >>= 1) acc += __shfl_down(acc, off, 64);
        if (lane == 0) {
            float b = (task < 128) ? ea_b1[row] : eg_b1[row];
            float h = fmaxf(acc + b, 0.0f);
            if (task < 128) hA[row] = h; else hG[row] = h;
        }
    }
    __syncthreads();
    // output layers: 192 row-dots, 48 per wave
    for (int q = 0; q < 48; ++q) {
        int task = wave + 4 * q;
        int row; const float* W; const float* hsrc;
        if (task < 64)       { row = task;       W = ea_w2; hsrc = hA;  }
        else if (task < 128) { row = task - 64;  W = eg_w2; hsrc = hG;  }
        else                 { row = task - 128; W = out_w; hsrc = cmb; }
        float2 wv = ((const float2*)(W + row * 128))[lane];
        float2 hv = ((const float2*)hsrc)[lane];
        float acc = wv.x * hv.x + wv.y * hv.y;
        #pragma unroll
        for (int off = 32; off > 0; off >>= 1) acc += __shfl_down(acc, off, 64);
        if (lane == 0) {
            if (task < 64)       aout[row] = acc + ea_b2[row];
            else if (task < 128) gout[row] = acc + eg_b2[row];
            else                 d_out[row] = acc + out_b[row];
        }
    }
    __syncthreads();
    if (t < 64) {
        float diff = aout[t] - gout[t];
        float sq = diff * diff;
        #pragma unroll
        for (int off = 32; off > 0; off >>= 1) sq += __shfl_down(sq, off, 64);
        if (t == 0) d_out[64] = sq * (1.0f / 64.0f);
    }
}

extern "C" void kernel_launch(void* const* d_in, const int* in_sizes, int n_in,
                              void* d_out, int out_size, void* d_ws, size_t ws_size,
                              hipStream_t stream) {
    (void)in_sizes; (void)n_in; (void)out_size; (void)ws_size;
    const float* x      = (const float*)d_in[0];
    const int*   step_p = (const int*)  d_in[1];
    const float* proto  = (const float*)d_in[2];
    const float* edges  = (const float*)d_in[3];
    const float* ages   = (const float*)d_in[4];
    const float* in_w   = (const float*)d_in[5];
    const float* in_b   = (const float*)d_in[6];
    const float* out_w  = (const float*)d_in[7];
    const float* out_b  = (const float*)d_in[8];
    const float* ea_w1  = (const float*)d_in[9];
    const float* ea_b1  = (const float*)d_in[10];
    const float* ea_w2  = (const float*)d_in[11];
    const float* ea_b2  = (const float*)d_in[12];
    const float* eg_w1  = (const float*)d_in[13];
    const float* eg_b1  = (const float*)d_in[14];
    const float* eg_w2  = (const float*)d_in[15];
    const float* eg_b2  = (const float*)d_in[16];

    float* ws      = (float*)d_ws;
    float* signal  = ws;
    float* dists   = ws + 128;
    float* partial = ws + 8320;
    float* topd    = ws + 41088;
    int*   topi    = (int*)(ws + 41096);
    int*   nlist   = (int*)(ws + 41104);
    int*   listIdx = (int*)(ws + 41112);
    float* listA   = ws + 49304;
    float* out     = (float*)d_out;

    k_signal <<<dim3(1),   dim3(128), 0, stream>>>(x, in_w, in_b, signal);
    k_dist   <<<dim3(256), dim3(256), 0, stream>>>(proto, signal, dists, partial);
    k_topcoef<<<dim3(1),   dim3(512), 0, stream>>>(dists, edges, ages, step_p,
                                                   topd, topi, nlist, listIdx, listA);
    k_final  <<<dim3(1),   dim3(256), 0, stream>>>(proto, signal, partial, topd, topi,
                                                   nlist, listIdx, listA, edges, ages, step_p,
                                                   ea_w1, ea_b1, ea_w2, ea_b2,
                                                   eg_w1, eg_b1, eg_w2, eg_b2,
                                                   out_w, out_b, out);
}